// Round 3
// baseline (309.944 us; speedup 1.0000x reference)
//
#include <hip/hip_runtime.h>

#define THREADS 256
#define NBLK 512
#define CAP 384
#define EST_ITERS 16      // 16 iters * 1024 floats = 16384-sample block-local estimate
#define EPS 1e-10
#define THRES 4.0f
#define SMALLN (1 << 22)

typedef float vf4 __attribute__((ext_vector_type(4)));

__device__ __forceinline__ double wave_sum(double v) {
#pragma unroll
  for (int off = 32; off > 0; off >>= 1) v += __shfl_down(v, off, 64);
  return v;
}

// blockDim.x must be 256 (4 waves). Safe to call repeatedly.
__device__ __forceinline__ double block_sum(double v, double* lds) {
  v = wave_sum(v);
  const int lane = threadIdx.x & 63;
  const int wid = threadIdx.x >> 6;
  __syncthreads();
  if (lane == 0) lds[wid] = v;
  __syncthreads();
  return lds[0] + lds[1] + lds[2] + lds[3];
}

// Device-scope generation-counting grid barrier. bar[0]=count, bar[1]=gen.
// ALL blocks must be co-resident (guaranteed: 512 blocks, capacity >= 4/CU).
__device__ __forceinline__ void grid_sync(unsigned* bar, unsigned nblk) {
  __syncthreads();
  if (threadIdx.x == 0) {
    __threadfence();  // release prior global writes device-wide
    unsigned g = __hip_atomic_load(&bar[1], __ATOMIC_RELAXED, __HIP_MEMORY_SCOPE_AGENT);
    unsigned v = __hip_atomic_fetch_add(&bar[0], 1u, __ATOMIC_ACQ_REL, __HIP_MEMORY_SCOPE_AGENT);
    if (v == nblk - 1u) {
      __hip_atomic_store(&bar[0], 0u, __ATOMIC_RELAXED, __HIP_MEMORY_SCOPE_AGENT);
      __hip_atomic_store(&bar[1], g + 1u, __ATOMIC_RELEASE, __HIP_MEMORY_SCOPE_AGENT);
    } else {
      while (__hip_atomic_load(&bar[1], __ATOMIC_ACQUIRE, __HIP_MEMORY_SCOPE_AGENT) == g) {
        __builtin_amdgcn_s_sleep(8);
      }
    }
    __threadfence();  // acquire side
  }
  __syncthreads();
}

__global__ void k_init(unsigned* __restrict__ bar) {
  if (threadIdx.x < 2) bar[threadIdx.x] = 0u;
}

__global__ void __launch_bounds__(THREADS, 4) k_fused(
    const float* __restrict__ x, float* __restrict__ out, long n,
    const float* __restrict__ gamma, const float* __restrict__ beta,
    unsigned* __restrict__ bar,
    double* __restrict__ pS, double* __restrict__ pSS,
    double* __restrict__ pM, double* __restrict__ pT, int* __restrict__ pO,
    double* __restrict__ pD, double* __restrict__ pE, double* __restrict__ pF) {
  __shared__ double lds[4];
  __shared__ float lcand[CAP];
  __shared__ int lcnt;
  const int b = blockIdx.x;
  const unsigned nblk = gridDim.x;
  const long nv4 = n >> 2;
  const long vpb = (nv4 + nblk - 1) / nblk;
  const long v0 = (long)b * vpb;
  long v1 = v0 + vpb;
  if (v1 > nv4) v1 = nv4;
  const float4* xv = (const float4*)x;
  const bool last = (b == (int)nblk - 1);

  if (threadIdx.x == 0) lcnt = 0;
  __syncthreads();

  // ---- Phase A0: block-local estimate over the first EST_ITERS strides ----
  double es = 0.0, ess = 0.0;
  long iter_end = v0 + (long)EST_ITERS * THREADS;
  if (iter_end > v1) iter_end = v1;
  for (long i = v0 + threadIdx.x; i < iter_end; i += THREADS) {
    float4 v = xv[i];
    double a = v.x, bb = v.y, c = v.z, d = v.w;
    es += (a + bb) + (c + d);
    ess += (a * a + bb * bb) + (c * c + d * d);
  }
  es = block_sum(es, lds);
  ess = block_sum(ess, lds);
  const long ecount = (iter_end - v0) * 4;
  double mhat = 0.0, th = 0.0;
  int ovf = 0;
  if (ecount >= 4096) {
    double ne = (double)ecount;
    mhat = es / ne;
    double var = (ess - es * es / ne) / (ne - 1.0);
    double sig = var > 0.0 ? sqrt(var) : 0.0;
    th = 3.2 * sig;
    if (!(th > 0.0)) ovf = 1;
  } else {
    ovf = 1;  // too few samples -> force fallback
  }
  const float mhf = (float)mhat;
  const float thf = (float)th;

  // ---- Phase A: main scan (sum/ss + candidate collection into LDS) ----
  double s = 0.0, ss = 0.0;
  if (!ovf) {
    for (long i = v0 + threadIdx.x; i < v1; i += THREADS) {
      float4 v = xv[i];
      double a = v.x, bb = v.y, c = v.z, d = v.w;
      s += (a + bb) + (c + d);
      ss += (a * a + bb * bb) + (c * c + d * d);
      if (fabsf(v.x - mhf) > thf) { int k = atomicAdd(&lcnt, 1); if (k < CAP) lcand[k] = v.x; }
      if (fabsf(v.y - mhf) > thf) { int k = atomicAdd(&lcnt, 1); if (k < CAP) lcand[k] = v.y; }
      if (fabsf(v.z - mhf) > thf) { int k = atomicAdd(&lcnt, 1); if (k < CAP) lcand[k] = v.z; }
      if (fabsf(v.w - mhf) > thf) { int k = atomicAdd(&lcnt, 1); if (k < CAP) lcand[k] = v.w; }
    }
    if (last) {
      for (long i = nv4 * 4 + threadIdx.x; i < n; i += THREADS) {
        float f = x[i];
        double a = f;
        s += a;
        ss += a * a;
        if (fabsf(f - mhf) > thf) { int k = atomicAdd(&lcnt, 1); if (k < CAP) lcand[k] = f; }
      }
    }
  } else {
    for (long i = v0 + threadIdx.x; i < v1; i += THREADS) {
      float4 v = xv[i];
      double a = v.x, bb = v.y, c = v.z, d = v.w;
      s += (a + bb) + (c + d);
      ss += (a * a + bb * bb) + (c * c + d * d);
    }
    if (last) {
      for (long i = nv4 * 4 + threadIdx.x; i < n; i += THREADS) {
        double a = x[i];
        s += a;
        ss += a * a;
      }
    }
  }
  s = block_sum(s, lds);
  ss = block_sum(ss, lds);
  if (threadIdx.x == 0) {
    pS[b] = s;
    pSS[b] = ss;
    pM[b] = mhat;
    pT[b] = th;
    pO[b] = (ovf || lcnt > CAP) ? 1 : 0;
  }

  grid_sync(bar, nblk);  // ---- sync 1 ----

  // ---- Phase B: redundant global finalize of pass 1 + coverage check ----
  double gs = 0.0, gss = 0.0;
  for (int i = threadIdx.x; i < (int)nblk; i += THREADS) { gs += pS[i]; gss += pSS[i]; }
  gs = block_sum(gs, lds);
  gss = block_sum(gss, lds);
  const double nd = (double)n;
  const double mean1 = gs / nd;
  const double var1 = (gss - gs * gs / nd) / (nd - 1.0);
  const double r1d = 1.0 / sqrt(var1 + EPS);
  double bad = 0.0;
  for (int i = threadIdx.x; i < (int)nblk; i += THREADS) {
    double cond = (pT[i] + fabs(mean1 - pM[i])) * r1d;
    if (pO[i] != 0 || !(cond < 3.999)) bad += 1.0;
  }
  bad = block_sum(bad, lds);
  const bool fast = (bad == 0.0);  // identical on every block
  const float m1f = (float)mean1;
  const float r1f = (float)r1d;

  double os = 0.0, oss = 0.0, oc = 0.0;
  if (fast) {
    // outlier stats from LDS candidates, exact reference rule
    int cnt = lcnt < CAP ? lcnt : CAP;
    for (int t = threadIdx.x; t < cnt; t += THREADS) {
      float v = lcand[t];
      float nf = (v - m1f) * r1f;
      if (!(nf < THRES && nf > -THRES)) { double a = v; os += a; oss += a * a; oc += 1.0; }
    }
  } else {
    // full masked rescan (slab should be L3-resident)
    for (long i = v0 + threadIdx.x; i < v1; i += THREADS) {
      float4 v = xv[i];
      float nf;
      nf = (v.x - m1f) * r1f;
      if (nf < THRES && nf > -THRES) { double a = v.x; os += a; oss += a * a; oc += 1.0; }
      nf = (v.y - m1f) * r1f;
      if (nf < THRES && nf > -THRES) { double a = v.y; os += a; oss += a * a; oc += 1.0; }
      nf = (v.z - m1f) * r1f;
      if (nf < THRES && nf > -THRES) { double a = v.z; os += a; oss += a * a; oc += 1.0; }
      nf = (v.w - m1f) * r1f;
      if (nf < THRES && nf > -THRES) { double a = v.w; os += a; oss += a * a; oc += 1.0; }
    }
    if (last) {
      for (long i = nv4 * 4 + threadIdx.x; i < n; i += THREADS) {
        float f = x[i];
        float nf = (f - m1f) * r1f;
        if (nf < THRES && nf > -THRES) { double a = f; os += a; oss += a * a; oc += 1.0; }
      }
    }
  }
  os = block_sum(os, lds);
  oss = block_sum(oss, lds);
  oc = block_sum(oc, lds);
  if (threadIdx.x == 0) { pD[b] = os; pE[b] = oss; pF[b] = oc; }

  grid_sync(bar, nblk);  // ---- sync 2 ----

  // ---- Phase C: redundant finalize of pass 2 + apply ----
  double t1 = 0.0, t2 = 0.0, t3 = 0.0;
  for (int i = threadIdx.x; i < (int)nblk; i += THREADS) { t1 += pD[i]; t2 += pE[i]; t3 += pF[i]; }
  t1 = block_sum(t1, lds);
  t2 = block_sum(t2, lds);
  t3 = block_sum(t3, lds);
  double s2, ss2, c2;
  if (fast) { s2 = gs - t1; ss2 = gss - t2; c2 = nd - t3; }
  else      { s2 = t1;      ss2 = t2;       c2 = t3; }
  const double mean2 = s2 / c2;
  const double var2 = (ss2 - s2 * s2 / c2) / (c2 - 1.0);
  const float m2f = (float)mean2;
  const float r2f = (float)(1.0 / sqrt(var2 + EPS));
  const float g = gamma[0];
  const float bb = beta[0];
  float4* ov = (float4*)out;
  for (long i = v0 + threadIdx.x; i < v1; i += THREADS) {
    float4 v = xv[i];
    vf4 t;
    t.x = g * (v.x - m2f) * r2f + bb;
    t.y = g * (v.y - m2f) * r2f + bb;
    t.z = g * (v.z - m2f) * r2f + bb;
    t.w = g * (v.w - m2f) * r2f + bb;
    __builtin_nontemporal_store(t, (vf4*)&ov[i]);
  }
  if (last) {
    for (long i = nv4 * 4 + threadIdx.x; i < n; i += THREADS) {
      float t = g * (x[i] - m2f) * r2f + bb;
      __builtin_nontemporal_store(t, &out[i]);
    }
  }
}

// ---------------- small-n fallback pipeline (scalar, robust) ----------------
__global__ void __launch_bounds__(THREADS) k_r1(
    const float* __restrict__ x, long n, double* __restrict__ pA, double* __restrict__ pB) {
  __shared__ double lds[4];
  double s = 0.0, ss = 0.0;
  const long stride = (long)gridDim.x * blockDim.x;
  for (long i = (long)blockIdx.x * blockDim.x + threadIdx.x; i < n; i += stride) {
    double a = x[i];
    s += a;
    ss += a * a;
  }
  s = block_sum(s, lds);
  ss = block_sum(ss, lds);
  if (threadIdx.x == 0) { pA[blockIdx.x] = s; pB[blockIdx.x] = ss; }
}

__global__ void __launch_bounds__(THREADS) k_f1(
    const double* __restrict__ pA, const double* __restrict__ pB, int nblk,
    double n, double* __restrict__ fin) {
  __shared__ double lds[4];
  double s = 0.0, ss = 0.0;
  for (int i = threadIdx.x; i < nblk; i += blockDim.x) { s += pA[i]; ss += pB[i]; }
  s = block_sum(s, lds);
  ss = block_sum(ss, lds);
  if (threadIdx.x == 0) {
    double mean1 = s / n;
    double var1 = (ss - s * s / n) / (n - 1.0);
    fin[0] = mean1;
    fin[1] = 1.0 / sqrt(var1 + EPS);
  }
}

__global__ void __launch_bounds__(THREADS) k_r2(
    const float* __restrict__ x, long n, const double* __restrict__ fin,
    double* __restrict__ pA, double* __restrict__ pB, double* __restrict__ pC) {
  __shared__ double lds[4];
  const float m1 = (float)fin[0];
  const float r1 = (float)fin[1];
  double s = 0.0, ss = 0.0, c = 0.0;
  const long stride = (long)gridDim.x * blockDim.x;
  for (long i = (long)blockIdx.x * blockDim.x + threadIdx.x; i < n; i += stride) {
    float f = x[i];
    float nf = (f - m1) * r1;
    if (nf < THRES && nf > -THRES) { double a = f; s += a; ss += a * a; c += 1.0; }
  }
  s = block_sum(s, lds);
  ss = block_sum(ss, lds);
  c = block_sum(c, lds);
  if (threadIdx.x == 0) { pA[blockIdx.x] = s; pB[blockIdx.x] = ss; pC[blockIdx.x] = c; }
}

__global__ void __launch_bounds__(THREADS) k_f2(
    const double* __restrict__ pA, const double* __restrict__ pB,
    const double* __restrict__ pC, int nblk, double* __restrict__ fin) {
  __shared__ double lds[4];
  double s = 0.0, ss = 0.0, c = 0.0;
  for (int i = threadIdx.x; i < nblk; i += blockDim.x) { s += pA[i]; ss += pB[i]; c += pC[i]; }
  s = block_sum(s, lds);
  ss = block_sum(ss, lds);
  c = block_sum(c, lds);
  if (threadIdx.x == 0) {
    double mean2 = s / c;
    double var2 = (ss - s * s / c) / (c - 1.0);
    fin[2] = mean2;
    fin[3] = 1.0 / sqrt(var2 + EPS);
  }
}

__global__ void __launch_bounds__(THREADS) k_ap(
    const float* __restrict__ x, float* __restrict__ out, long n,
    const double* __restrict__ fin,
    const float* __restrict__ gamma, const float* __restrict__ beta) {
  const float m2 = (float)fin[2];
  const float r2 = (float)fin[3];
  const float g = gamma[0];
  const float bb = beta[0];
  const long stride = (long)gridDim.x * blockDim.x;
  for (long i = (long)blockIdx.x * blockDim.x + threadIdx.x; i < n; i += stride) {
    out[i] = g * (x[i] - m2) * r2 + bb;
  }
}

extern "C" void kernel_launch(void* const* d_in, const int* in_sizes, int n_in,
                              void* d_out, int out_size, void* d_ws, size_t ws_size,
                              hipStream_t stream) {
  const float* x = (const float*)d_in[0];
  const float* gamma = (const float*)d_in[1];
  const float* beta = (const float*)d_in[2];
  float* out = (float*)d_out;
  const long n = (long)in_sizes[0];

  char* base = (char*)d_ws;
  unsigned* bar = (unsigned*)base;
  double* pS = (double*)(base + 256);
  double* pSS = pS + NBLK;
  double* pM = pSS + NBLK;
  double* pT = pM + NBLK;
  double* pD = pT + NBLK;
  double* pE = pD + NBLK;
  double* pF = pE + NBLK;
  int* pO = (int*)(pF + NBLK);
  size_t needed = 256 + (size_t)NBLK * (7 * sizeof(double) + sizeof(int));

  if (n >= SMALLN && (n >> 2) >= NBLK && ws_size >= needed) {
    k_init<<<1, 64, 0, stream>>>(bar);
    k_fused<<<NBLK, THREADS, 0, stream>>>(x, out, n, gamma, beta, bar,
                                          pS, pSS, pM, pT, pO, pD, pE, pF);
  } else {
    // small-n scalar pipeline
    int nblk = 64;
    double* fin = (double*)(base);        // 4 doubles
    double* fA = (double*)(base + 256);
    double* fB = fA + nblk;
    double* fC = fB + nblk;
    k_r1<<<nblk, THREADS, 0, stream>>>(x, n, fA, fB);
    k_f1<<<1, THREADS, 0, stream>>>(fA, fB, nblk, (double)n, fin);
    k_r2<<<nblk, THREADS, 0, stream>>>(x, n, fin, fA, fB, fC);
    k_f2<<<1, THREADS, 0, stream>>>(fA, fB, fC, nblk, fin);
    k_ap<<<nblk, THREADS, 0, stream>>>(x, out, n, fin, gamma, beta);
  }
}